// Round 1
// baseline (189.624 us; speedup 1.0000x reference)
//
#include <hip/hip_runtime.h>

#define B_   16
#define C_   128
#define N_   2304      // 48*48
#define ZR   256       // 2*C
#define KSPLIT 4
#define KPB  (N_/KSPLIT)   // 576
#define KC   64

// ---------------- kernel 1: inverse column norms ----------------
__global__ __launch_bounds__(256) void norms_k(const float* __restrict__ pred,
                                               const float* __restrict__ targ,
                                               float* __restrict__ rx,
                                               float* __restrict__ ry) {
    int b = blockIdx.x / 9;
    int n = (blockIdx.x % 9) * 256 + threadIdx.x;  // 9*256 == 2304
    const float* p = pred + (size_t)b * C_ * N_ + n;
    const float* t = targ + (size_t)b * C_ * N_ + n;
    float sp = 0.f, st = 0.f;
#pragma unroll 8
    for (int c = 0; c < C_; ++c) {
        float a = p[(size_t)c * N_];
        float d = t[(size_t)c * N_];
        sp = fmaf(a, a, sp);
        st = fmaf(d, d, st);
    }
    rx[b * N_ + n] = rsqrtf(fmaxf(sp, 1e-20f));
    ry[b * N_ + n] = rsqrtf(fmaxf(st, 1e-20f));
}

// ---------------- kernel 2: W = Z Z^T per batch, k-split ----------------
// Z rows 0..127  = pred[b]  * rx   (C x N)
// Z rows 128..255= target[b]* ry
// block: 64 threads (1 wave). Each block: one 64x64 tile of W for one
// (batch, k-split). 8x8 accumulators per thread.
__global__ __launch_bounds__(64) void gram_k(const float* __restrict__ pred,
                                             const float* __restrict__ targ,
                                             const float* __restrict__ rx,
                                             const float* __restrict__ ry,
                                             float* __restrict__ W) {
    int blk = blockIdx.x;
    int s  = blk & 3;          // k-split
    int tj = (blk >> 2) & 3;   // col tile
    int ti = (blk >> 4) & 3;   // row tile
    int b  = blk >> 6;         // batch
    int K0 = s * KPB;

    int t  = threadIdx.x;
    int tx = t & 7;
    int ty = t >> 3;

    __shared__ float4 ldsI[64 * 16];
    __shared__ float4 ldsJ[64 * 16];

    const float* rxb = rx + b * N_;
    const float* ryb = ry + b * N_;
    const float* pb  = pred + (size_t)b * C_ * N_;
    const float* tb  = targ + (size_t)b * C_ * N_;

    float acc[8][8];
#pragma unroll
    for (int a = 0; a < 8; ++a)
#pragma unroll
        for (int bb = 0; bb < 8; ++bb) acc[a][bb] = 0.f;

    int lr = t >> 4;          // 0..3  (row sub-index for staging)
    int kb = (t & 15) * 4;    // 0..60 (k offset for staging)
    int gI = kb >> 2;         // granule index 0..15

    for (int ch = 0; ch < KPB / KC; ++ch) {
        int kbase = K0 + ch * KC;
        // ---- stage: 64 rows x 64 k of each side, swizzled granules ----
#pragma unroll
        for (int it = 0; it < 16; ++it) {
            int r = it * 4 + lr;             // 0..63 within tile
            // I side (rows ti*64 + r of Z)
            {
                int zr = ti * 64 + r;
                const float* src = (zr < C_) ? (pb + (size_t)zr * N_)
                                             : (tb + (size_t)(zr - C_) * N_);
                const float* sc  = (zr < C_) ? rxb : ryb;
                float4 v = *(const float4*)(src + kbase + kb);
                float4 w = *(const float4*)(sc + kbase + kb);
                v.x *= w.x; v.y *= w.y; v.z *= w.z; v.w *= w.w;
                ldsI[r * 16 + (gI ^ (r >> 3))] = v;
            }
            // J side (rows tj*64 + r of Z)
            {
                int zr = tj * 64 + r;
                const float* src = (zr < C_) ? (pb + (size_t)zr * N_)
                                             : (tb + (size_t)(zr - C_) * N_);
                const float* sc  = (zr < C_) ? rxb : ryb;
                float4 v = *(const float4*)(src + kbase + kb);
                float4 w = *(const float4*)(sc + kbase + kb);
                v.x *= w.x; v.y *= w.y; v.z *= w.z; v.w *= w.w;
                ldsJ[r * 16 + (gI ^ (r >> 3))] = v;
            }
        }
        __syncthreads();
        // ---- compute: 64 k per chunk, float4 over k ----
#pragma unroll
        for (int k4 = 0; k4 < 16; ++k4) {
            float4 aI[8], aJ[8];
#pragma unroll
            for (int a = 0; a < 8; ++a)
                aI[a] = ldsI[(ty * 8 + a) * 16 + (k4 ^ ty)];
#pragma unroll
            for (int bb = 0; bb < 8; ++bb)
                aJ[bb] = ldsJ[(tx * 8 + bb) * 16 + (k4 ^ tx)];
#pragma unroll
            for (int a = 0; a < 8; ++a)
#pragma unroll
                for (int bb = 0; bb < 8; ++bb) {
                    acc[a][bb] = fmaf(aI[a].x, aJ[bb].x, acc[a][bb]);
                    acc[a][bb] = fmaf(aI[a].y, aJ[bb].y, acc[a][bb]);
                    acc[a][bb] = fmaf(aI[a].z, aJ[bb].z, acc[a][bb]);
                    acc[a][bb] = fmaf(aI[a].w, aJ[bb].w, acc[a][bb]);
                }
        }
        __syncthreads();
    }

    // ---- write 64x64 tile: W[s][b][ti*64+row][tj*64+col], float4 stores ----
    float* Wsb = W + ((size_t)(s * B_ + b)) * ZR * ZR;
#pragma unroll
    for (int a = 0; a < 8; ++a) {
        int row = ti * 64 + ty * 8 + a;
        int col = tj * 64 + tx * 8;
        float4 w0 = make_float4(acc[a][0], acc[a][1], acc[a][2], acc[a][3]);
        float4 w1 = make_float4(acc[a][4], acc[a][5], acc[a][6], acc[a][7]);
        *(float4*)(Wsb + (size_t)row * ZR + col)     = w0;
        *(float4*)(Wsb + (size_t)row * ZR + col + 4) = w1;
    }
}

// ---------------- kernel 3: per-batch S1 - S2 (double) ----------------
__global__ __launch_bounds__(256) void reduce_k(const float* __restrict__ W,
                                                double* __restrict__ partial) {
    int b = blockIdx.x;
    int t = threadIdx.x;
    double s1 = 0.0, s2 = 0.0;
    for (int idx = t; idx < C_ * C_; idx += 256) {
        int i = idx >> 7;
        int j = idx & 127;
        float ga = 0.f, gb = 0.f, pij = 0.f, pji = 0.f;
#pragma unroll
        for (int s = 0; s < KSPLIT; ++s) {
            const float* Wsb = W + ((size_t)(s * B_ + b)) * ZR * ZR;
            ga  += Wsb[(size_t)i * ZR + j];                  // (A A^T)[i,j]
            gb  += Wsb[(size_t)(C_ + i) * ZR + (C_ + j)];    // (B B^T)[i,j]
            pij += Wsb[(size_t)(C_ + i) * ZR + j];           // P[i,j] = (B A^T)[i,j]
            pji += Wsb[(size_t)i * ZR + (C_ + j)];           // (A B^T)[i,j] = P[j,i]
        }
        s1 += (double)ga * (double)gb;
        s2 += (double)pij * (double)pji;
    }
    double v = s1 - s2;
    // block reduction (4 waves)
    __shared__ double sd[4];
#pragma unroll
    for (int o = 32; o > 0; o >>= 1) v += __shfl_down(v, o, 64);
    if ((t & 63) == 0) sd[t >> 6] = v;
    __syncthreads();
    if (t == 0) partial[b] = sd[0] + sd[1] + sd[2] + sd[3];
}

// ---------------- kernel 4: final scalar ----------------
__global__ void final_k(const double* __restrict__ partial, float* __restrict__ out) {
    if (threadIdx.x == 0 && blockIdx.x == 0) {
        double s = 0.0;
        for (int b = 0; b < B_; ++b) s += partial[b];
        double loss = 2.0 * s / ((double)B_ * (double)N_ * (double)N_);
        out[0] = (float)loss;
    }
}

extern "C" void kernel_launch(void* const* d_in, const int* in_sizes, int n_in,
                              void* d_out, int out_size, void* d_ws, size_t ws_size,
                              hipStream_t stream) {
    const float* pred = (const float*)d_in[0];
    const float* targ = (const float*)d_in[1];
    float* out = (float*)d_out;

    // workspace layout (floats):
    //   rx: B_*N_            = 36864
    //   ry: B_*N_            = 36864
    //   W : KSPLIT*B_*256*256 = 4,194,304
    //   partial: 16 doubles
    float* ws   = (float*)d_ws;
    float* rx   = ws;
    float* ry   = ws + (size_t)B_ * N_;
    float* W    = ws + (size_t)2 * B_ * N_;
    double* prt = (double*)(ws + (size_t)2 * B_ * N_ + (size_t)KSPLIT * B_ * ZR * ZR);

    norms_k<<<B_ * 9, 256, 0, stream>>>(pred, targ, rx, ry);
    gram_k<<<B_ * 16 * KSPLIT, 64, 0, stream>>>(pred, targ, rx, ry, W);
    reduce_k<<<B_, 256, 0, stream>>>(W, prt);
    final_k<<<1, 64, 0, stream>>>(prt, out);
}

// Round 2
// 91.221 us; speedup vs baseline: 2.0787x; 2.0787x over previous
//
#include <hip/hip_runtime.h>

#define B_   16
#define C_   128
#define N_   2304      // 48*48
#define ZR   256       // 2*C
#define KS   2         // k-splits (grid)
#define KPB  (N_/KS)   // 1152 per block
#define KC   64        // k per staged chunk
#define NCH  (KPB/KC)  // 18 chunks

// ---------------- kernel 1: inverse column norms ----------------
// grid: B_*36 blocks, 256 threads. Each block: 64 columns of one batch,
// 4 waves split C into quarters, LDS reduce.
__global__ __launch_bounds__(256) void norms_k(const float* __restrict__ pred,
                                               const float* __restrict__ targ,
                                               float* __restrict__ rx,
                                               float* __restrict__ ry) {
    int blk = blockIdx.x;
    int b  = blk / 36;
    int ng = blk % 36;
    int tx = threadIdx.x & 63;
    int ty = threadIdx.x >> 6;           // 0..3
    int n  = ng * 64 + tx;
    const float* p  = pred + (size_t)b * C_ * N_ + n;
    const float* tg = targ + (size_t)b * C_ * N_ + n;
    float sp = 0.f, st = 0.f;
#pragma unroll 8
    for (int c = ty * 32; c < ty * 32 + 32; ++c) {
        float a = p[(size_t)c * N_];
        float d = tg[(size_t)c * N_];
        sp = fmaf(a, a, sp);
        st = fmaf(d, d, st);
    }
    __shared__ float rp[4][64], rt[4][64];
    rp[ty][tx] = sp;
    rt[ty][tx] = st;
    __syncthreads();
    if (ty == 0) {
        float SP = rp[0][tx] + rp[1][tx] + rp[2][tx] + rp[3][tx];
        float ST = rt[0][tx] + rt[1][tx] + rt[2][tx] + rt[3][tx];
        rx[b * N_ + n] = rsqrtf(fmaxf(SP, 1e-20f));
        ry[b * N_ + n] = rsqrtf(fmaxf(ST, 1e-20f));
    }
}

// ---------------- kernel 2: W = Z Z^T per batch, k-split ----------------
// 256 threads = 4 waves, one 64x64 tile of W per block. Waves split the
// 16 k-granules of each staged chunk (4 each); partial accs reduced via LDS.
__global__ __launch_bounds__(256, 2) void gram_k(const float* __restrict__ pred,
                                                 const float* __restrict__ targ,
                                                 const float* __restrict__ rx,
                                                 const float* __restrict__ ry,
                                                 float* __restrict__ W) {
    int blk = blockIdx.x;
    int s  = blk & 1;          // k-split
    int tj = (blk >> 1) & 3;   // col tile
    int ti = (blk >> 3) & 3;   // row tile
    int b  = blk >> 5;         // batch
    int K0 = s * KPB;

    int t    = threadIdx.x;
    int w    = t >> 6;         // wave 0..3
    int lane = t & 63;
    int tx   = lane & 7;
    int ty   = lane >> 3;

    __shared__ float4 lds[2048];           // 32 KB: ldsI[1024] | ldsJ[1024]
    float4* ldsI = lds;
    float4* ldsJ = lds + 1024;

    const float* rxb = rx + b * N_;
    const float* ryb = ry + b * N_;
    const float* pb  = pred + (size_t)b * C_ * N_;
    const float* tb  = targ + (size_t)b * C_ * N_;

    const float* srcI = (ti < 2) ? (pb + (size_t)(ti * 64) * N_)
                                 : (tb + (size_t)(ti * 64 - C_) * N_);
    const float* scI  = (ti < 2) ? rxb : ryb;
    const float* srcJ = (tj < 2) ? (pb + (size_t)(tj * 64) * N_)
                                 : (tb + (size_t)(tj * 64 - C_) * N_);
    const float* scJ  = (tj < 2) ? rxb : ryb;

    float acc[8][8];
#pragma unroll
    for (int a = 0; a < 8; ++a)
#pragma unroll
        for (int bb = 0; bb < 8; ++bb) acc[a][bb] = 0.f;

    int g  = t & 15;   // granule 0..15 (constant per thread -> scale loaded once)
    int r0 = t >> 4;   // 0..15

    for (int ch = 0; ch < NCH; ++ch) {
        int kbase = K0 + ch * KC;
        float4 sI = *(const float4*)(scI + kbase + g * 4);
        float4 sJ = *(const float4*)(scJ + kbase + g * 4);
        // ---- stage 64 rows x 64 k of each side, swizzled granules ----
#pragma unroll
        for (int it = 0; it < 4; ++it) {
            int r = it * 16 + r0;
            float4 v = *(const float4*)(srcI + (size_t)r * N_ + kbase + g * 4);
            v.x *= sI.x; v.y *= sI.y; v.z *= sI.z; v.w *= sI.w;
            ldsI[r * 16 + (g ^ (r >> 3))] = v;
            float4 u = *(const float4*)(srcJ + (size_t)r * N_ + kbase + g * 4);
            u.x *= sJ.x; u.y *= sJ.y; u.z *= sJ.z; u.w *= sJ.w;
            ldsJ[r * 16 + (g ^ (r >> 3))] = u;
        }
        __syncthreads();
        // ---- compute: wave w handles granules w*4 .. w*4+3 ----
#pragma unroll
        for (int kk = 0; kk < 4; ++kk) {
            int k4 = w * 4 + kk;
            float4 aI[8], aJ[8];
#pragma unroll
            for (int a = 0; a < 8; ++a)
                aI[a] = ldsI[(ty * 8 + a) * 16 + (k4 ^ ty)];
#pragma unroll
            for (int bb = 0; bb < 8; ++bb)
                aJ[bb] = ldsJ[(tx * 8 + bb) * 16 + (k4 ^ tx)];
#pragma unroll
            for (int a = 0; a < 8; ++a)
#pragma unroll
                for (int bb = 0; bb < 8; ++bb) {
                    acc[a][bb] = fmaf(aI[a].x, aJ[bb].x, acc[a][bb]);
                    acc[a][bb] = fmaf(aI[a].y, aJ[bb].y, acc[a][bb]);
                    acc[a][bb] = fmaf(aI[a].z, aJ[bb].z, acc[a][bb]);
                    acc[a][bb] = fmaf(aI[a].w, aJ[bb].w, acc[a][bb]);
                }
        }
        __syncthreads();
    }

    // ---- cross-wave reduction via LDS, then tile write ----
    float4* redv = lds;   // 2048 float4 = 8192 floats; need 2x 1024 float4
    if (w < 2) {
#pragma unroll
        for (int a = 0; a < 8; ++a) {
            int row = ty * 8 + a;
            int base = w * 1024 + row * 16 + tx * 2;
            redv[base]     = make_float4(acc[a][0], acc[a][1], acc[a][2], acc[a][3]);
            redv[base + 1] = make_float4(acc[a][4], acc[a][5], acc[a][6], acc[a][7]);
        }
    }
    __syncthreads();
    if (w >= 2) {
        int wb = w - 2;
#pragma unroll
        for (int a = 0; a < 8; ++a) {
            int row = ty * 8 + a;
            int base = wb * 1024 + row * 16 + tx * 2;
            float4 q0 = redv[base];
            q0.x += acc[a][0]; q0.y += acc[a][1]; q0.z += acc[a][2]; q0.w += acc[a][3];
            redv[base] = q0;
            float4 q1 = redv[base + 1];
            q1.x += acc[a][4]; q1.y += acc[a][5]; q1.z += acc[a][6]; q1.w += acc[a][7];
            redv[base + 1] = q1;
        }
    }
    __syncthreads();
    float* Wsb = W + ((size_t)(s * B_ + b)) * ZR * ZR;
#pragma unroll
    for (int it = 0; it < 4; ++it) {
        int fidx = it * 256 + t;        // 0..1023 float4 granules of the tile
        int row  = fidx >> 4;
        int gg   = fidx & 15;
        float4 x0 = redv[fidx];
        float4 x1 = redv[1024 + fidx];
        x0.x += x1.x; x0.y += x1.y; x0.z += x1.z; x0.w += x1.w;
        *(float4*)(Wsb + (size_t)(ti * 64 + row) * ZR + tj * 64 + gg * 4) = x0;
    }
}

// ---------------- kernel 3: per-(batch,segment) S1 - S2 (double) ----------------
#define RB 8    // blocks per batch
__global__ __launch_bounds__(256) void reduce_k(const float* __restrict__ W,
                                                double* __restrict__ partial) {
    int blk = blockIdx.x;           // B_*RB = 128
    int b   = blk / RB;
    int seg = blk % RB;
    int t   = threadIdx.x;
    double s1 = 0.0, s2 = 0.0;
#pragma unroll
    for (int ii = 0; ii < (C_ * C_ / RB / 256); ++ii) {   // 2048/256 = 8
        int idx = seg * 2048 + ii * 256 + t;
        int i = idx >> 7;
        int j = idx & 127;
        float ga = 0.f, gb = 0.f, pij = 0.f, pji = 0.f;
#pragma unroll
        for (int s = 0; s < KS; ++s) {
            const float* Wsb = W + ((size_t)(s * B_ + b)) * ZR * ZR;
            ga  += Wsb[(size_t)i * ZR + j];
            gb  += Wsb[(size_t)(C_ + i) * ZR + (C_ + j)];
            pij += Wsb[(size_t)(C_ + i) * ZR + j];
            pji += Wsb[(size_t)i * ZR + (C_ + j)];
        }
        s1 += (double)ga * (double)gb;
        s2 += (double)pij * (double)pji;
    }
    double v = s1 - s2;
    __shared__ double sd[4];
#pragma unroll
    for (int o = 32; o > 0; o >>= 1) v += __shfl_down(v, o, 64);
    if ((t & 63) == 0) sd[t >> 6] = v;
    __syncthreads();
    if (t == 0) partial[blk] = sd[0] + sd[1] + sd[2] + sd[3];
}

// ---------------- kernel 4: final scalar ----------------
__global__ void final_k(const double* __restrict__ partial, float* __restrict__ out) {
    if (threadIdx.x == 0 && blockIdx.x == 0) {
        double s = 0.0;
        for (int i = 0; i < B_ * RB; ++i) s += partial[i];
        double loss = 2.0 * s / ((double)B_ * (double)N_ * (double)N_);
        out[0] = (float)loss;
    }
}

extern "C" void kernel_launch(void* const* d_in, const int* in_sizes, int n_in,
                              void* d_out, int out_size, void* d_ws, size_t ws_size,
                              hipStream_t stream) {
    const float* pred = (const float*)d_in[0];
    const float* targ = (const float*)d_in[1];
    float* out = (float*)d_out;

    // workspace layout (floats):
    //   rx: B_*N_ = 36864 | ry: B_*N_ | W: KS*B_*256*256 = 2,097,152 | partial
    float* ws   = (float*)d_ws;
    float* rx   = ws;
    float* ry   = ws + (size_t)B_ * N_;
    float* W    = ws + (size_t)2 * B_ * N_;
    double* prt = (double*)(ws + (size_t)2 * B_ * N_ + (size_t)KS * B_ * ZR * ZR);

    norms_k<<<B_ * 36, 256, 0, stream>>>(pred, targ, rx, ry);
    gram_k<<<B_ * 16 * KS, 256, 0, stream>>>(pred, targ, rx, ry, W);
    reduce_k<<<B_ * RB, 256, 0, stream>>>(W, prt);
    final_k<<<1, 64, 0, stream>>>(prt, out);
}

// Round 3
// 42.126 us; speedup vs baseline: 4.5013x; 2.1654x over previous
//
#include <hip/hip_runtime.h>

#define B_   16
#define C_   128
#define N_   2304      // 48*48
#define ZR   256       // 2*C
#define KS   4         // k-splits for gram grid
#define KPB  (N_/KS)   // 576
#define KC   64        // k per staged chunk (64 bf16 = 8 granules of 16B)
#define NCH  (KPB/KC)  // 9

typedef __bf16 bf16x8 __attribute__((ext_vector_type(8)));
typedef float  f32x4  __attribute__((ext_vector_type(4)));

__device__ __forceinline__ unsigned rne16(float f) {
    unsigned u = __float_as_uint(f);
    return (u + 0x7FFFu + ((u >> 16) & 1u)) >> 16;   // round-to-nearest-even bf16
}

// ---------------- kernel 1: fused column-norm + normalize + bf16 convert ----
// grid: B_*36 blocks, 256 threads; each block: 64 columns of one batch,
// both pred (Z rows 0..127) and targ (Z rows 128..255).
__global__ __launch_bounds__(256) void nc_k(const float* __restrict__ pred,
                                            const float* __restrict__ targ,
                                            ushort* __restrict__ Z) {
    int blk = blockIdx.x;
    int b  = blk / 36;
    int n0 = (blk % 36) * 64;
    int t  = threadIdx.x;
    int cq = t >> 6;        // 0..3 (== wave id)
    int n  = t & 63;

    __shared__ float sbuf[128][64];
    __shared__ float rp[4][64];
    __shared__ float rn[64];

    for (int side = 0; side < 2; ++side) {
        const float* src = (side ? targ : pred) + (size_t)b * C_ * N_;
        if (side) __syncthreads();          // sbuf reuse: wait for convert reads
        float s = 0.f;
#pragma unroll 8
        for (int k = 0; k < 32; ++k) {
            int c = cq * 32 + k;
            float v = src[(size_t)c * N_ + n0 + n];
            sbuf[c][n] = v;
            s = fmaf(v, v, s);
        }
        rp[cq][n] = s;
        __syncthreads();
        if (cq == 0)
            rn[n] = rsqrtf(fmaxf(rp[0][n] + rp[1][n] + rp[2][n] + rp[3][n], 1e-20f));
        __syncthreads();
        // convert + write: 2 bf16 per store (uint), coalesced
        int c0 = t >> 5;        // 0..7
        int n2 = t & 31;        // 0..31 (pairs of n)
        unsigned rowbase = (unsigned)(b * ZR + side * C_);
#pragma unroll
        for (int i = 0; i < 16; ++i) {
            int c = i * 8 + c0;
            float2 v = *(const float2*)&sbuf[c][2 * n2];
            float2 r = *(const float2*)&rn[2 * n2];
            unsigned pk = rne16(v.x * r.x) | (rne16(v.y * r.y) << 16);
            *((unsigned*)(Z + (size_t)(rowbase + c) * N_ + n0) + n2) = pk;
        }
    }
}

// ---------------- kernel 2: W += Z_q Z_q^T via bf16 MFMA ----------------
// grid: B_*KS*4 = 256 blocks, 256 threads (4 waves). Block = (batch, ksplit,
// quadrant qi,qj). Each wave: 64x64 of the 128x128 quadrant, 16 MFMA tiles.
// Staging: global_load_lds width16, linear LDS dest + involution-swizzled
// global source; frag reads apply the same swizzle (conflict-free).
__global__ __launch_bounds__(256) void gram_k(const ushort* __restrict__ Z,
                                              float* __restrict__ W) {
    int blk = blockIdx.x;
    int q = blk & 3;
    int s = (blk >> 2) & 3;
    int b = blk >> 4;
    int qi = q >> 1, qj = q & 1;
    bool same = (qi == qj);

    int t    = threadIdx.x;
    int lane = t & 63;
    int w    = t >> 6;
    int wr = (w >> 1) * 64;
    int wc = (w & 1) * 64;

    __shared__ float4 lds[4096];            // 64 KB: 2 dbuf x (A 1024 | B 1024)

    const ushort* Zb   = Z + (size_t)b * ZR * N_;
    const ushort* srcA = Zb + (size_t)(qi * C_) * N_;
    const ushort* srcB = Zb + (size_t)(qj * C_) * N_;
    int Boff = same ? 0 : 1024;

    f32x4 acc[4][4];
#pragma unroll
    for (int m = 0; m < 4; ++m)
#pragma unroll
        for (int n = 0; n < 4; ++n) acc[m][n] = (f32x4){0.f, 0.f, 0.f, 0.f};

    auto stage = [&](int dbuf, int ch) {
        int kc0 = s * KPB + ch * KC;        // bf16-element offset in row
        float4* base = lds + dbuf * 2048;
#pragma unroll
        for (int it = 0; it < 4; ++it) {
            int r  = it * 32 + (t >> 3);
            int gl = (t & 7) ^ (r & 7);     // logical granule, pre-swizzled
            const ushort* g = srcA + (size_t)r * N_ + kc0 + gl * 8;
            __builtin_amdgcn_global_load_lds(
                (const __attribute__((address_space(1))) void*)g,
                (__attribute__((address_space(3))) void*)(base + it * 256 + t),
                16, 0, 0);
        }
        if (!same) {
#pragma unroll
            for (int it = 0; it < 4; ++it) {
                int r  = it * 32 + (t >> 3);
                int gl = (t & 7) ^ (r & 7);
                const ushort* g = srcB + (size_t)r * N_ + kc0 + gl * 8;
                __builtin_amdgcn_global_load_lds(
                    (const __attribute__((address_space(1))) void*)g,
                    (__attribute__((address_space(3))) void*)(base + 1024 + it * 256 + t),
                    16, 0, 0);
            }
        }
    };

    auto compute = [&](int dbuf) {
        const bf16x8* L = (const bf16x8*)(lds + dbuf * 2048);
#pragma unroll
        for (int kk = 0; kk < 2; ++kk) {
            bf16x8 aA[4], aB[4];
            int gl = kk * 4 + (lane >> 4);
#pragma unroll
            for (int m = 0; m < 4; ++m) {
                int r = wr + m * 16 + (lane & 15);
                aA[m] = L[r * 8 + (gl ^ (r & 7))];
            }
#pragma unroll
            for (int n = 0; n < 4; ++n) {
                int r = wc + n * 16 + (lane & 15);
                aB[n] = L[Boff + r * 8 + (gl ^ (r & 7))];
            }
#pragma unroll
            for (int m = 0; m < 4; ++m)
#pragma unroll
                for (int n = 0; n < 4; ++n)
                    acc[m][n] = __builtin_amdgcn_mfma_f32_16x16x32_bf16(
                        aA[m], aB[n], acc[m][n], 0, 0, 0);
        }
    };

    stage(0, 0);
    int buf = 0;
    for (int ch = 0; ch < NCH; ++ch) {
        __syncthreads();                    // drains vmcnt: chunk ch landed
        if (ch + 1 < NCH) stage(buf ^ 1, ch + 1);
        compute(buf);
        buf ^= 1;
    }

    // accumulate into W[b] (fp32 atomics; W memset to 0 each launch)
    float* Wb = W + (size_t)b * ZR * ZR;
#pragma unroll
    for (int m = 0; m < 4; ++m) {
        int row0 = qi * C_ + wr + m * 16 + (lane >> 4) * 4;
#pragma unroll
        for (int n = 0; n < 4; ++n) {
            int col = qj * C_ + wc + n * 16 + (lane & 15);
#pragma unroll
            for (int v = 0; v < 4; ++v)
                atomicAdd(&Wb[(size_t)(row0 + v) * ZR + col], acc[m][n][v]);
        }
    }
}

// ---------------- kernel 3: per-(batch,seg) S1 - S2 in double ----------------
__global__ __launch_bounds__(256) void reduce_k(const float* __restrict__ W,
                                                double* __restrict__ prt) {
    int blk = blockIdx.x;       // 128 = 16 b x 8 seg
    int b   = blk >> 3;
    int seg = blk & 7;
    int t   = threadIdx.x;
    const float* Wb = W + (size_t)b * ZR * ZR;
    double s1 = 0.0, s2 = 0.0;
#pragma unroll
    for (int ii = 0; ii < 8; ++ii) {
        int idx = seg * 2048 + ii * 256 + t;   // 0..16383 over (i,j)
        int i = idx >> 7;
        int j = idx & 127;
        float ga  = Wb[(size_t)i * ZR + j];                // (A A^T)[i,j]
        float gb  = Wb[(size_t)(C_ + i) * ZR + (C_ + j)];  // (B B^T)[i,j]
        float pij = Wb[(size_t)(C_ + i) * ZR + j];         // P[i,j]
        float pji = Wb[(size_t)i * ZR + (C_ + j)];         // P[j,i]
        s1 += (double)ga * (double)gb;
        s2 += (double)pij * (double)pji;
    }
    double v = s1 - s2;
    __shared__ double sd[4];
#pragma unroll
    for (int o = 32; o > 0; o >>= 1) v += __shfl_down(v, o, 64);
    if ((t & 63) == 0) sd[t >> 6] = v;
    __syncthreads();
    if (t == 0) prt[blk] = sd[0] + sd[1] + sd[2] + sd[3];
}

// ---------------- kernel 4: final scalar ----------------
__global__ __launch_bounds__(128) void final_k(const double* __restrict__ prt,
                                               float* __restrict__ out) {
    int t = threadIdx.x;
    double v = prt[t];          // 128 partials
#pragma unroll
    for (int o = 32; o > 0; o >>= 1) v += __shfl_down(v, o, 64);
    __shared__ double sd[2];
    if ((t & 63) == 0) sd[t >> 6] = v;
    __syncthreads();
    if (t == 0) {
        double s = sd[0] + sd[1];
        out[0] = (float)(2.0 * s / ((double)B_ * (double)N_ * (double)N_));
    }
}

extern "C" void kernel_launch(void* const* d_in, const int* in_sizes, int n_in,
                              void* d_out, int out_size, void* d_ws, size_t ws_size,
                              hipStream_t stream) {
    const float* pred = (const float*)d_in[0];
    const float* targ = (const float*)d_in[1];
    float* out = (float*)d_out;

    // workspace layout (bytes):
    //   Z  : B_*ZR*N_*2      = 18,874,368  (bf16, normalized)
    //   W  : B_*ZR*ZR*4      =  4,194,304  (fp32, atomic-accumulated)
    //   prt: 128 doubles     =      1,024
    char* ws = (char*)d_ws;
    ushort* Z   = (ushort*)ws;
    float*  W   = (float*)(ws + (size_t)B_ * ZR * N_ * 2);
    double* prt = (double*)(ws + (size_t)B_ * ZR * N_ * 2 + (size_t)B_ * ZR * ZR * 4);

    nc_k<<<B_ * 36, 256, 0, stream>>>(pred, targ, Z);
    hipMemsetAsync(W, 0, (size_t)B_ * ZR * ZR * 4, stream);
    gram_k<<<B_ * KS * 4, 256, 0, stream>>>(Z, W);
    reduce_k<<<128, 256, 0, stream>>>(W, prt);
    final_k<<<1, 128, 0, stream>>>(prt, out);
}

// Round 4
// 38.872 us; speedup vs baseline: 4.8781x; 1.0837x over previous
//
#include <hip/hip_runtime.h>

#define B_   16
#define C_   128
#define N_   2304      // 48*48
#define ZR   256       // 2*C
#define KS   4         // k-splits for gram grid
#define KPB  (N_/KS)   // 576
#define KC   64        // k per staged chunk (64 bf16 = 8 granules of 16B)
#define NCH  (KPB/KC)  // 9
#define QT   16384     // 128*128 floats per quadrant tile

typedef __bf16 bf16x8 __attribute__((ext_vector_type(8)));
typedef float  f32x4  __attribute__((ext_vector_type(4)));

__device__ __forceinline__ unsigned rne16(float f) {
    unsigned u = __float_as_uint(f);
    return (u + 0x7FFFu + ((u >> 16) & 1u)) >> 16;   // round-to-nearest-even bf16
}

// ---------------- kernel 1: fused column-norm + normalize + bf16 convert ----
// grid: B_*36 blocks, 256 threads; each block: 64 columns of one batch,
// both pred (Z rows 0..127) and targ (Z rows 128..255).
__global__ __launch_bounds__(256) void nc_k(const float* __restrict__ pred,
                                            const float* __restrict__ targ,
                                            ushort* __restrict__ Z) {
    int blk = blockIdx.x;
    int b  = blk / 36;
    int n0 = (blk % 36) * 64;
    int t  = threadIdx.x;
    int cq = t >> 6;        // 0..3 (== wave id)
    int n  = t & 63;

    __shared__ float sbuf[128][64];
    __shared__ float rp[4][64];
    __shared__ float rn[64];

    for (int side = 0; side < 2; ++side) {
        const float* src = (side ? targ : pred) + (size_t)b * C_ * N_;
        if (side) __syncthreads();          // sbuf reuse: wait for convert reads
        float s = 0.f;
#pragma unroll 8
        for (int k = 0; k < 32; ++k) {
            int c = cq * 32 + k;
            float v = src[(size_t)c * N_ + n0 + n];
            sbuf[c][n] = v;
            s = fmaf(v, v, s);
        }
        rp[cq][n] = s;
        __syncthreads();
        if (cq == 0)
            rn[n] = rsqrtf(fmaxf(rp[0][n] + rp[1][n] + rp[2][n] + rp[3][n], 1e-20f));
        __syncthreads();
        // convert + write: 2 bf16 per store (uint), coalesced
        int c0 = t >> 5;        // 0..7
        int n2 = t & 31;        // 0..31 (pairs of n)
        unsigned rowbase = (unsigned)(b * ZR + side * C_);
#pragma unroll
        for (int i = 0; i < 16; ++i) {
            int c = i * 8 + c0;
            float2 v = *(const float2*)&sbuf[c][2 * n2];
            float2 r = *(const float2*)&rn[2 * n2];
            unsigned pk = rne16(v.x * r.x) | (rne16(v.y * r.y) << 16);
            *((unsigned*)(Z + (size_t)(rowbase + c) * N_ + n0) + n2) = pk;
        }
    }
}

// ---------------- kernel 2: partial Grams via bf16 MFMA ----------------
// grid: B_*KS*3 = 192 blocks, 256 threads (4 waves). Block = (batch, ksplit,
// quadrant q): q=0 GA=A A^T, q=1 GB=B B^T, q=2 P=B A^T. Each wave: 64x64 of
// the 128x128 quadrant. Staging: global_load_lds width16, linear LDS dest +
// involution-swizzled global source; frag reads apply the same swizzle.
// Output: plain float stores to per-(s,b,q) 128x128 tile (no init needed).
__global__ __launch_bounds__(256) void gram_k(const ushort* __restrict__ Z,
                                              float* __restrict__ Wp) {
    int blk = blockIdx.x;
    int q = blk % 3;
    int s = (blk / 3) & 3;
    int b = blk / 12;
    bool same = (q < 2);

    int t    = threadIdx.x;
    int lane = t & 63;
    int w    = t >> 6;
    int wr = (w >> 1) * 64;
    int wc = (w & 1) * 64;

    __shared__ float4 lds[4096];            // 64 KB: 2 dbuf x (A 1024 | B 1024)

    const ushort* Zb = Z + (size_t)b * ZR * N_;
    // A-operand rows = output rows i; B-operand rows = output cols j
    // q=0: (A,A)  q=1: (B,B)  q=2: P[i,j]=(B A^T)[i,j] -> rows=targ, cols=pred
    const ushort* srcA = (q == 0) ? Zb : Zb + (size_t)C_ * N_;
    const ushort* srcB = (q == 1) ? Zb + (size_t)C_ * N_ : Zb;
    int Boff = same ? 0 : 1024;

    f32x4 acc[4][4];
#pragma unroll
    for (int m = 0; m < 4; ++m)
#pragma unroll
        for (int n = 0; n < 4; ++n) acc[m][n] = (f32x4){0.f, 0.f, 0.f, 0.f};

    auto stage = [&](int dbuf, int ch) {
        int kc0 = s * KPB + ch * KC;        // bf16-element offset in row
        float4* base = lds + dbuf * 2048;
#pragma unroll
        for (int it = 0; it < 4; ++it) {
            int r  = it * 32 + (t >> 3);
            int gl = (t & 7) ^ (r & 7);     // logical granule, pre-swizzled
            const ushort* g = srcA + (size_t)r * N_ + kc0 + gl * 8;
            __builtin_amdgcn_global_load_lds(
                (const __attribute__((address_space(1))) void*)g,
                (__attribute__((address_space(3))) void*)(base + it * 256 + t),
                16, 0, 0);
        }
        if (!same) {
#pragma unroll
            for (int it = 0; it < 4; ++it) {
                int r  = it * 32 + (t >> 3);
                int gl = (t & 7) ^ (r & 7);
                const ushort* g = srcB + (size_t)r * N_ + kc0 + gl * 8;
                __builtin_amdgcn_global_load_lds(
                    (const __attribute__((address_space(1))) void*)g,
                    (__attribute__((address_space(3))) void*)(base + 1024 + it * 256 + t),
                    16, 0, 0);
            }
        }
    };

    auto compute = [&](int dbuf) {
        const bf16x8* L = (const bf16x8*)(lds + dbuf * 2048);
#pragma unroll
        for (int kk = 0; kk < 2; ++kk) {
            bf16x8 aA[4], aB[4];
            int gl = kk * 4 + (lane >> 4);
#pragma unroll
            for (int m = 0; m < 4; ++m) {
                int r = wr + m * 16 + (lane & 15);
                aA[m] = L[r * 8 + (gl ^ (r & 7))];
            }
#pragma unroll
            for (int n = 0; n < 4; ++n) {
                int r = wc + n * 16 + (lane & 15);
                aB[n] = L[Boff + r * 8 + (gl ^ (r & 7))];
            }
#pragma unroll
            for (int m = 0; m < 4; ++m)
#pragma unroll
                for (int n = 0; n < 4; ++n)
                    acc[m][n] = __builtin_amdgcn_mfma_f32_16x16x32_bf16(
                        aA[m], aB[n], acc[m][n], 0, 0, 0);
        }
    };

    stage(0, 0);
    int buf = 0;
    for (int ch = 0; ch < NCH; ++ch) {
        __syncthreads();                    // drains vmcnt: chunk ch landed
        if (ch + 1 < NCH) stage(buf ^ 1, ch + 1);
        compute(buf);
        buf ^= 1;
    }

    // plain stores: every element of the (s,b,q) tile written exactly once
    float* Wq = Wp + (((size_t)(s * B_ + b) * 3 + q) << 14);
#pragma unroll
    for (int m = 0; m < 4; ++m) {
        int row0 = wr + m * 16 + (lane >> 4) * 4;
#pragma unroll
        for (int n = 0; n < 4; ++n) {
            int col = wc + n * 16 + (lane & 15);
#pragma unroll
            for (int v = 0; v < 4; ++v)
                Wq[(size_t)(row0 + v) * C_ + col] = acc[m][n][v];
        }
    }
}

// ---------------- kernel 3: per-(batch,seg) S1 - S2 in double ----------------
__global__ __launch_bounds__(256) void reduce_k(const float* __restrict__ Wp,
                                                double* __restrict__ prt) {
    int blk = blockIdx.x;       // 128 = 16 b x 8 seg
    int b   = blk >> 3;
    int seg = blk & 7;
    int t   = threadIdx.x;
    double s1 = 0.0, s2 = 0.0;
#pragma unroll
    for (int ii = 0; ii < 8; ++ii) {
        int idx = seg * 2048 + ii * 256 + t;   // 0..16383 over (i,j)
        int i = idx >> 7;
        int j = idx & 127;
        float ga = 0.f, gb = 0.f, pij = 0.f, pji = 0.f;
#pragma unroll
        for (int s = 0; s < KS; ++s) {
            const float* Wb = Wp + (((size_t)(s * B_ + b)) * 3 << 14);
            ga  += Wb[idx];                       // GA[i,j]
            gb  += Wb[QT + idx];                  // GB[i,j]
            pij += Wb[2 * QT + idx];              // P[i,j]
            pji += Wb[2 * QT + j * C_ + i];       // P[j,i]  (L1-resident slab)
        }
        s1 += (double)ga * (double)gb;
        s2 += (double)pij * (double)pji;
    }
    double v = s1 - s2;
    __shared__ double sd[4];
#pragma unroll
    for (int o = 32; o > 0; o >>= 1) v += __shfl_down(v, o, 64);
    if ((t & 63) == 0) sd[t >> 6] = v;
    __syncthreads();
    if (t == 0) prt[blk] = sd[0] + sd[1] + sd[2] + sd[3];
}

// ---------------- kernel 4: final scalar ----------------
__global__ __launch_bounds__(128) void final_k(const double* __restrict__ prt,
                                               float* __restrict__ out) {
    int t = threadIdx.x;
    double v = prt[t];          // 128 partials
#pragma unroll
    for (int o = 32; o > 0; o >>= 1) v += __shfl_down(v, o, 64);
    __shared__ double sd[2];
    if ((t & 63) == 0) sd[t >> 6] = v;
    __syncthreads();
    if (t == 0) {
        double s = sd[0] + sd[1];
        out[0] = (float)(2.0 * s / ((double)B_ * (double)N_ * (double)N_));
    }
}

extern "C" void kernel_launch(void* const* d_in, const int* in_sizes, int n_in,
                              void* d_out, int out_size, void* d_ws, size_t ws_size,
                              hipStream_t stream) {
    const float* pred = (const float*)d_in[0];
    const float* targ = (const float*)d_in[1];
    float* out = (float*)d_out;

    // workspace layout (bytes):
    //   Z  : B_*ZR*N_*2            = 18,874,368  (bf16, normalized)
    //   Wp : KS*B_*3*QT*4          = 12,582,912  (fp32 partial quadrants)
    //   prt: 128 doubles           =      1,024
    char* ws = (char*)d_ws;
    ushort* Z   = (ushort*)ws;
    float*  Wp  = (float*)(ws + (size_t)B_ * ZR * N_ * 2);
    double* prt = (double*)(ws + (size_t)B_ * ZR * N_ * 2
                               + (size_t)KS * B_ * 3 * QT * 4);

    nc_k<<<B_ * 36, 256, 0, stream>>>(pred, targ, Z);
    gram_k<<<B_ * KS * 3, 256, 0, stream>>>(Z, Wp);
    reduce_k<<<128, 256, 0, stream>>>(Wp, prt);
    final_k<<<1, 128, 0, stream>>>(prt, out);
}